// Round 2
// baseline (2178.028 us; speedup 1.0000x reference)
//
#include <hip/hip_runtime.h>
#include <stdint.h>

#define N_ROWS 262144
#define D_DIM  1024
#define H_DIM  512
#define N_SEG  512

typedef __attribute__((ext_vector_type(4))) float  f32x4;
typedef __attribute__((ext_vector_type(8))) __bf16 bf16x8;
typedef __attribute__((ext_vector_type(8))) unsigned short ushort8;

static __device__ __forceinline__ unsigned short f2bf(float f) {
  union { float f; uint32_t u; } c; c.f = f;
  return (unsigned short)((c.u + 0x7FFFu + ((c.u >> 16) & 1u)) >> 16);  // RNE
}

static __device__ __forceinline__ float fast_tanh(float u) {
  return 1.0f - 2.0f / (__expf(2.0f * u) + 1.0f);
}

// ---------------- kernel 0: W1,W2 f32 -> bf16 ----------------
__global__ void cvt_w(const float* __restrict__ W1, const float* __restrict__ W2,
                      unsigned short* __restrict__ wbf) {
  int idx = blockIdx.x * 256 + threadIdx.x;
  if (idx < H_DIM * D_DIM) wbf[idx] = f2bf(W1[idx]);
  else                     wbf[idx] = f2bf(W2[idx - H_DIM * D_DIM]);
}

// ---------------- kernel 1: a[i] = (tanh(xW1^T) * softmax(xW2^T)) @ W3^T ----
// 64 rows/block, full H=512 (8 waves x 64 cols). K pipelined in 16 subtiles of
// 64, double-buffered 8KB LDS bufs; x-loads held 3 subtiles deep in regs; W
// ping-pong prefetched 1 K-step ahead from L2. Barriers: lgkmcnt(0)+s_barrier
// ONLY (no vmcnt drain).
#define PACKW(dst, A, B) do { \
    dst[0]=f2bf(A[0]); dst[1]=f2bf(A[1]); dst[2]=f2bf(A[2]); dst[3]=f2bf(A[3]); \
    dst[4]=f2bf(B[0]); dst[5]=f2bf(B[1]); dst[6]=f2bf(B[2]); dst[7]=f2bf(B[3]); \
  } while (0)

#define KSTEP(K, BUFOFF, WUSE, WLD) do { \
    const int _kn = (K) + 1; \
    _Pragma("unroll") \
    for (int q = 0; q < 8; ++q) \
      WLD[q] = *(const bf16x8*)(wbf + woff[q] + _kn * 32); \
    bf16x8 afr[4]; \
    _Pragma("unroll") \
    for (int rf = 0; rf < 4; ++rf) \
      afr[rf] = *(const bf16x8*)(lds + (BUFOFF) + ((abase + (rf << 11) + (((K) & 1) << 6)) ^ swz)); \
    __builtin_amdgcn_s_setprio(1); \
    _Pragma("unroll") \
    for (int cf = 0; cf < 4; ++cf) { \
      _Pragma("unroll") \
      for (int rf = 0; rf < 4; ++rf) { \
        au[rf][cf] = __builtin_amdgcn_mfma_f32_16x16x32_bf16(afr[rf], WUSE[cf],     au[rf][cf], 0, 0, 0); \
        av[rf][cf] = __builtin_amdgcn_mfma_f32_16x16x32_bf16(afr[rf], WUSE[4 + cf], av[rf][cf], 0, 0, 0); \
      } \
    } \
    __builtin_amdgcn_s_setprio(0); \
  } while (0)

#define ENDBAR() do { \
    asm volatile("s_waitcnt lgkmcnt(0)" ::: "memory"); \
    __builtin_amdgcn_s_barrier(); \
    asm volatile("" ::: "memory"); \
  } while (0)

__launch_bounds__(512, 2)
__global__ void alpha_kernel(const float* __restrict__ x,
                             const unsigned short* __restrict__ wbf,
                             const float* __restrict__ W3,
                             float* __restrict__ a_out)
{
  __shared__ unsigned char lds[2 * 8192 + 6144];
  const int tid  = threadIdx.x;
  const int lane = tid & 63;
  const int wid  = tid >> 6;                   // 0..7 -> col slice wid*64
  const int l15  = lane & 15;
  const int lg   = lane >> 4;                  // 0..3
  const int row0 = blockIdx.x << 6;

  // staging: subtile t = 64 rows x 64 k-cols; thread -> (row sr, 8-elem chunk sc)
  const int sr = tid >> 3;
  const int sc = tid & 7;
  const float* xrow = x + ((size_t)(row0 + sr) << 10) + (sc << 3);
  const uint32_t wbyte = ((uint32_t)(sr << 7) + (uint32_t)(sc << 4)) ^ ((uint32_t)(sr & 7) << 4);

  uint32_t woff[8];                            // 32-bit offsets from uniform wbf base
  #pragma unroll
  for (int cf = 0; cf < 4; ++cf) {
    uint32_t o = (uint32_t)((((wid << 6) + (cf << 4) + l15) << 10) + (lg << 3));
    woff[cf]     = o;                          // W1
    woff[4 + cf] = o + (uint32_t)(H_DIM * D_DIM); // W2
  }

  f32x4 au[4][4], av[4][4];
  #pragma unroll
  for (int rf = 0; rf < 4; ++rf)
    #pragma unroll
    for (int cf = 0; cf < 4; ++cf) {
      au[rf][cf] = (f32x4){0.f, 0.f, 0.f, 0.f};
      av[rf][cf] = (f32x4){0.f, 0.f, 0.f, 0.f};
    }

  const uint32_t abase = ((uint32_t)l15 << 7) + ((uint32_t)lg << 4);
  const uint32_t swz   = ((uint32_t)(l15 & 7)) << 4;

  // ---- prologue: subtile 0 -> buf0; subtiles 1,2 in regs; W k=0 -> WA ----
  f32x4 xa0, xa1, xb0, xb1;
  { const float* p = xrow;       xa0 = *(const f32x4*)p; xa1 = *(const f32x4*)(p + 4); }
  { const float* p = xrow + 64;  xb0 = *(const f32x4*)p; xb1 = *(const f32x4*)(p + 4); }
  { ushort8 v; PACKW(v, xa0, xa1); *(ushort8*)(lds + wbyte) = v; }
  { const float* p = xrow + 128; xa0 = *(const f32x4*)p; xa1 = *(const f32x4*)(p + 4); }
  bf16x8 WA[8], WB[8];
  #pragma unroll
  for (int q = 0; q < 8; ++q) WA[q] = *(const bf16x8*)(wbf + woff[q]);
  ENDBAR();

  // ---- main pipeline: 16 subtiles, 2 K-steps each ----
  #pragma unroll 1
  for (int tt = 0; tt < 16; tt += 2) {
    // T = tt (even): compute buf0, stage subtile tt+1 (xb) -> buf1, load tt+3 -> xb
    {
      ushort8 v; PACKW(v, xb0, xb1);
      *(ushort8*)(lds + 8192 + wbyte) = v;
      if (tt < 13) { const float* p = xrow + ((tt + 3) << 6);
                     xb0 = *(const f32x4*)p; xb1 = *(const f32x4*)(p + 4); }
      KSTEP(tt * 2,     0, WA, WB);
      KSTEP(tt * 2 + 1, 0, WB, WA);
      ENDBAR();
    }
    // T = tt+1 (odd): compute buf1, stage subtile tt+2 (xa) -> buf0, load tt+4 -> xa
    {
      if (tt < 14) { ushort8 v; PACKW(v, xa0, xa1); *(ushort8*)(lds + wbyte) = v; }
      if (tt < 12) { const float* p = xrow + ((tt + 4) << 6);
                     xa0 = *(const f32x4*)p; xa1 = *(const f32x4*)(p + 4); }
      KSTEP(tt * 2 + 2, 8192, WA, WB);
      KSTEP(tt * 2 + 3, 8192, WB, WA);
      ENDBAR();
    }
  }

  // ---- epilogue: per-wave partial softmax stats over its 64 cols ----
  float w3v[4];
  #pragma unroll
  for (int cf = 0; cf < 4; ++cf) w3v[cf] = W3[(wid << 6) + (cf << 4) + l15];

  float* redm = (float*)(lds + 16384);
  float* reds = redm + 512;
  float* redn = redm + 1024;

  #pragma unroll
  for (int rf = 0; rf < 4; ++rf) {
    float mx[4], sj[4], nj[4];
    #pragma unroll
    for (int j = 0; j < 4; ++j)
      mx[j] = fmaxf(fmaxf(av[rf][0][j], av[rf][1][j]), fmaxf(av[rf][2][j], av[rf][3][j]));
    #pragma unroll
    for (int d = 1; d < 16; d <<= 1)
      #pragma unroll
      for (int j = 0; j < 4; ++j) mx[j] = fmaxf(mx[j], __shfl_xor(mx[j], d));
    #pragma unroll
    for (int j = 0; j < 4; ++j) { sj[j] = 0.f; nj[j] = 0.f; }
    #pragma unroll
    for (int cf = 0; cf < 4; ++cf)
      #pragma unroll
      for (int j = 0; j < 4; ++j) {
        float p  = __expf(av[rf][cf][j] - mx[j]);
        float tt2 = fast_tanh(au[rf][cf][j]);
        sj[j] += p;
        nj[j] += tt2 * p * w3v[cf];
      }
    #pragma unroll
    for (int d = 1; d < 16; d <<= 1)
      #pragma unroll
      for (int j = 0; j < 4; ++j) {
        sj[j] += __shfl_xor(sj[j], d);
        nj[j] += __shfl_xor(nj[j], d);
      }
    if (l15 == 0) {
      #pragma unroll
      for (int j = 0; j < 4; ++j) {
        int r = (rf << 4) + (lg << 2) + j;
        redm[(wid << 6) + r] = mx[j];
        reds[(wid << 6) + r] = sj[j];
        redn[(wid << 6) + r] = nj[j];
      }
    }
  }
  __syncthreads();
  if (tid < 64) {
    float m = redm[tid];
    #pragma unroll
    for (int wv = 1; wv < 8; ++wv) m = fmaxf(m, redm[(wv << 6) + tid]);
    float s = 0.f, n = 0.f;
    #pragma unroll
    for (int wv = 0; wv < 8; ++wv) {
      float sc2 = __expf(redm[(wv << 6) + tid] - m);
      s += reds[(wv << 6) + tid] * sc2;
      n += redn[(wv << 6) + tid] * sc2;
    }
    a_out[row0 + tid] = n / s;
  }
}

// ---------------- kernel 2: segment softmax weights ----------------
static __device__ __forceinline__ int lower_bound(const int* __restrict__ batch, int key) {
  int lo = 0, hi = N_ROWS;
  while (lo < hi) { int mid = (lo + hi) >> 1; if (batch[mid] < key) lo = mid + 1; else hi = mid; }
  return lo;
}

__global__ void seg_kernel(const float* __restrict__ a, const int* __restrict__ batch,
                           float* __restrict__ w) {
  __shared__ float sm[8];
  int b = blockIdx.x;
  int start = lower_bound(batch, b);
  int end   = lower_bound(batch, b + 1);
  int tid = threadIdx.x;

  float m = -3.4e38f;
  for (int i = start + tid; i < end; i += 256) m = fmaxf(m, a[i]);
  for (int d = 1; d < 64; d <<= 1) m = fmaxf(m, __shfl_xor(m, d));
  if ((tid & 63) == 0) sm[tid >> 6] = m;
  __syncthreads();
  m = fmaxf(fmaxf(sm[0], sm[1]), fmaxf(sm[2], sm[3]));

  float s = 0.f;
  for (int i = start + tid; i < end; i += 256) s += __expf(a[i] - m);
  for (int d = 1; d < 64; d <<= 1) s += __shfl_xor(s, d);
  if ((tid & 63) == 0) sm[4 + (tid >> 6)] = s;
  __syncthreads();
  s = sm[4] + sm[5] + sm[6] + sm[7];

  float rinv = 1.0f / s;
  for (int i = start + tid; i < end; i += 256) w[i] = __expf(a[i] - m) * rinv;
}

// ---------------- kernel 3: z[b] = sum_i w_i * x_i ----------------
__global__ void z_kernel(const float* __restrict__ x, const float* __restrict__ w,
                         const int* __restrict__ batch, float* __restrict__ z) {
  int b = blockIdx.x >> 2, part = blockIdx.x & 3;
  int start = lower_bound(batch, b);
  int end   = lower_bound(batch, b + 1);
  int len = end - start;
  int ps = start + ((len * part) >> 2);
  int pe = start + ((len * (part + 1)) >> 2);
  int col = threadIdx.x << 2;

  f32x4 acc = (f32x4){0.f, 0.f, 0.f, 0.f};
  for (int i = ps; i < pe; ++i) {
    f32x4 xv = *(const f32x4*)(x + ((size_t)i << 10) + col);
    float wi = w[i];
    acc += xv * wi;
  }
  float* zp = z + ((size_t)b << 10) + col;
  atomicAdd(zp + 0, acc[0]);
  atomicAdd(zp + 1, acc[1]);
  atomicAdd(zp + 2, acc[2]);
  atomicAdd(zp + 3, acc[3]);
}

// ---------------- launch ----------------
extern "C" void kernel_launch(void* const* d_in, const int* in_sizes, int n_in,
                              void* d_out, int out_size, void* d_ws, size_t ws_size,
                              hipStream_t stream) {
  const float* x     = (const float*)d_in[0];
  const int*   batch = (const int*)d_in[1];
  const float* W1    = (const float*)d_in[2];
  const float* W2    = (const float*)d_in[3];
  const float* W3    = (const float*)d_in[4];
  float* z = (float*)d_out;

  // ws layout: [0,2MB) W1|W2 bf16 ; [2MB,3MB) a[N] f32 ; [3MB,4MB) w[N] f32
  unsigned short* wbf = (unsigned short*)d_ws;
  float* a = (float*)((char*)d_ws + (2u << 20));
  float* w = (float*)((char*)d_ws + (3u << 20));

  hipMemsetAsync(d_out, 0, (size_t)N_SEG * D_DIM * sizeof(float), stream);

  cvt_w<<<(2 * H_DIM * D_DIM) / 256, 256, 0, stream>>>(W1, W2, wbf);

  alpha_kernel<<<N_ROWS / 64, 512, 0, stream>>>(x, wbf, W3, a);

  seg_kernel<<<N_SEG, 256, 0, stream>>>(a, batch, w);

  z_kernel<<<N_SEG * 4, 256, 0, stream>>>(x, w, batch, z);
}

// Round 4
// 1115.833 us; speedup vs baseline: 1.9519x; 1.9519x over previous
//
#include <hip/hip_runtime.h>
#include <stdint.h>

#define N_ROWS 262144
#define D_DIM  1024
#define H_DIM  512
#define N_SEG  512

typedef __attribute__((ext_vector_type(4)))  float  f32x4;
typedef __attribute__((ext_vector_type(16))) float  f32x16;
typedef __attribute__((ext_vector_type(8)))  __bf16 bf16x8;
typedef __attribute__((ext_vector_type(4)))  unsigned short u16x4;
typedef __attribute__((ext_vector_type(8)))  unsigned short u16x8;

static __device__ __forceinline__ unsigned short f2bf(float f) {
  union { float f; uint32_t u; } c; c.f = f;
  return (unsigned short)((c.u + 0x7FFFu + ((c.u >> 16) & 1u)) >> 16);  // RNE
}
static __device__ __forceinline__ float fast_tanh(float u) {
  return 1.0f - 2.0f / (__expf(2.0f * u) + 1.0f);
}

// ---------------- kernel 0: repack W1,W2 f32 -> bf16, frag-major ----------
// out elem index = m*524288 + kk*8192 + col*16 + hi*8 + e  <=  W_m[col][kk*16+hi*8+e]
// so one wave's (kk, 32-col slice) B-frag load is a single contiguous 1 KB line.
__global__ void cvt_w(const float* __restrict__ W1, const float* __restrict__ W2,
                      unsigned short* __restrict__ wbf) {
  int gid = blockIdx.x * 256 + threadIdx.x;      // 0..131071 frags of 8
  int hi  = gid & 1;
  int col = (gid >> 1) & 511;
  int kk  = (gid >> 10) & 63;
  int m   = gid >> 16;
  const float* src = (m ? W2 : W1) + col * 1024 + kk * 16 + hi * 8;
  u16x8 v;
  #pragma unroll
  for (int e = 0; e < 8; ++e) v[e] = f2bf(src[e]);
  *(u16x8*)(wbf + (size_t)gid * 8) = v;
}

// ---------------- kernel 1: a[i] = (tanh(xW1^T) * softmax(xW2^T)) @ W3^T ----
// 64 rows/block, 1024 thr, 16 waves x (64r x 32c x 2mat) via mfma 32x32x16.
// acc = 64 regs/thread -> 4 waves/SIMD. K in 16 subtiles of 64, dbuf LDS,
// x-loads 2 phases deep, W prefetch 1 kstep ahead. lgkm-only barriers.
#define ENDBAR() do { \
  asm volatile("s_waitcnt lgkmcnt(0)" ::: "memory"); \
  __builtin_amdgcn_s_barrier(); \
} while (0)

#define KST(BUFOFF, KK, WU1, WU2, WL1, WL2) do { \
  WL1 = *(const bf16x8*)(wbf + w1off + (((KK) + 1) << 13)); \
  WL2 = *(const bf16x8*)(wbf + w2off + (((KK) + 1) << 13)); \
  bf16x8 a0 = *(const bf16x8*)(lds + (BUFOFF) + ((ra0 + (((KK) & 3) << 5)) ^ swz)); \
  bf16x8 a1 = *(const bf16x8*)(lds + (BUFOFF) + ((ra0 + 4096 + (((KK) & 3) << 5)) ^ swz)); \
  __builtin_amdgcn_s_setprio(1); \
  au0 = __builtin_amdgcn_mfma_f32_32x32x16_bf16(a0, WU1, au0, 0, 0, 0); \
  av0 = __builtin_amdgcn_mfma_f32_32x32x16_bf16(a0, WU2, av0, 0, 0, 0); \
  au1 = __builtin_amdgcn_mfma_f32_32x32x16_bf16(a1, WU1, au1, 0, 0, 0); \
  av1 = __builtin_amdgcn_mfma_f32_32x32x16_bf16(a1, WU2, av1, 0, 0, 0); \
  __builtin_amdgcn_s_setprio(0); \
} while (0)

#define PACK4(DSTBYTE, Q) do { \
  u16x4 _v; _v[0]=f2bf(Q[0]); _v[1]=f2bf(Q[1]); _v[2]=f2bf(Q[2]); _v[3]=f2bf(Q[3]); \
  *(u16x4*)(lds + (DSTBYTE)) = _v; \
} while (0)

__launch_bounds__(1024, 4)
__global__ void alpha_kernel(const float* __restrict__ x,
                             const unsigned short* __restrict__ wbf,
                             const float* __restrict__ W3,
                             float* __restrict__ a_out)
{
  __shared__ unsigned char lds[32768 + 12288];   // 2 x 16KB bufs + 12KB reduce
  const int tid  = threadIdx.x;
  const int lane = tid & 63;
  const int wid  = tid >> 6;                     // 0..15 col group (32 cols)
  const int l31  = lane & 31;
  const int hi   = lane >> 5;
  const int row0 = blockIdx.x << 6;

  // staging: subtile = 64 rows x 64 k (bf16, 8KB). thread -> row sr, 4-float chunk sc
  const int sr = tid >> 4;                       // 0..63
  const int sc = tid & 15;                       // 0..15
  const float* xptr = x + ((size_t)(row0 + sr) << 10) + (sc << 2);
  const uint32_t wbyte = ((uint32_t)((sr << 7) + (sc << 3))) ^ (((uint32_t)(sr & 7)) << 4);

  // W frag offsets (elements), frag-major layout from cvt_w
  const int col = (wid << 5) + l31;
  const uint32_t w1off = (uint32_t)((col << 4) + (hi << 3));
  const uint32_t w2off = w1off + 524288u;

  f32x16 au0, au1, av0, av1;
  #pragma unroll
  for (int i = 0; i < 16; ++i) { au0[i]=0.f; au1[i]=0.f; av0[i]=0.f; av1[i]=0.f; }

  const uint32_t swz = (((uint32_t)(l31 & 7)) << 4);
  const uint32_t ra0 = (((uint32_t)l31) << 7) + (((uint32_t)hi) << 4);

  // prologue: sub0 -> buf0; sub1 -> regs; W kstep0 -> WA
  f32x4 xa = *(const f32x4*)xptr;
  f32x4 xb = *(const f32x4*)(xptr + 64);
  PACK4(wbyte, xa);
  bf16x8 WA1 = *(const bf16x8*)(wbf + w1off);
  bf16x8 WA2 = *(const bf16x8*)(wbf + w2off);
  bf16x8 WB1, WB2;
  ENDBAR();

  #pragma unroll 1
  for (int t = 0; t < 16; t += 2) {
    // even phase: compute buf0 (sub t); pack sub t+1 -> buf1; load sub t+2 -> xa
    if (t + 2 < 16) xa = *(const f32x4*)(xptr + ((t + 2) << 6));
    PACK4(16384 + wbyte, xb);
    KST(0, t * 4 + 0, WA1, WA2, WB1, WB2);
    KST(0, t * 4 + 1, WB1, WB2, WA1, WA2);
    KST(0, t * 4 + 2, WA1, WA2, WB1, WB2);
    KST(0, t * 4 + 3, WB1, WB2, WA1, WA2);
    ENDBAR();
    // odd phase: compute buf1 (sub t+1); pack sub t+2 -> buf0; load sub t+3 -> xb
    if (t + 3 < 16) xb = *(const f32x4*)(xptr + ((t + 3) << 6));
    if (t + 2 < 16) PACK4(wbyte, xa);
    KST(16384, t * 4 + 4, WA1, WA2, WB1, WB2);
    KST(16384, t * 4 + 5, WB1, WB2, WA1, WA2);
    KST(16384, t * 4 + 6, WA1, WA2, WB1, WB2);
    KST(16384, t * 4 + 7, WB1, WB2, WA1, WA2);
    ENDBAR();
  }

  // ---- epilogue: per-wave partial softmax stats over its 32 cols ----
  // C/D map (m74/m101): col = lane&31, row = (reg&3) + 8*(reg>>2) + 4*(lane>>5)
  float w3v = W3[col];
  float* redm = (float*)(lds + 32768);           // [16][64]
  float* reds = (float*)(lds + 32768 + 4096);
  float* redn = (float*)(lds + 32768 + 8192);

  #pragma unroll
  for (int rf = 0; rf < 2; ++rf) {
    const f32x16 U = rf ? au1 : au0;
    const f32x16 V = rf ? av1 : av0;
    float m_[16];
    #pragma unroll
    for (int r = 0; r < 16; ++r) m_[r] = V[r];
    #pragma unroll
    for (int d = 1; d < 32; d <<= 1)
      #pragma unroll
      for (int r = 0; r < 16; ++r) m_[r] = fmaxf(m_[r], __shfl_xor(m_[r], d));
    float s_[16], n_[16];
    #pragma unroll
    for (int r = 0; r < 16; ++r) {
      float p = __expf(V[r] - m_[r]);
      s_[r] = p;
      n_[r] = fast_tanh(U[r]) * p * w3v;
    }
    #pragma unroll
    for (int d = 1; d < 32; d <<= 1)
      #pragma unroll
      for (int r = 0; r < 16; ++r) { s_[r] += __shfl_xor(s_[r], d); n_[r] += __shfl_xor(n_[r], d); }
    if (l31 == 0) {
      #pragma unroll
      for (int r = 0; r < 16; ++r) {
        int row = rf * 32 + (r & 3) + ((r >> 2) << 3) + (hi << 2);
        redm[(wid << 6) + row] = m_[r];
        reds[(wid << 6) + row] = s_[r];
        redn[(wid << 6) + row] = n_[r];
      }
    }
  }
  __syncthreads();
  if (tid < 64) {
    float m = redm[tid];
    #pragma unroll
    for (int w = 1; w < 16; ++w) m = fmaxf(m, redm[(w << 6) + tid]);
    float s = 0.f, n = 0.f;
    #pragma unroll
    for (int w = 0; w < 16; ++w) {
      float sc2 = __expf(redm[(w << 6) + tid] - m);
      s += reds[(w << 6) + tid] * sc2;
      n += redn[(w << 6) + tid] * sc2;
    }
    a_out[row0 + tid] = n / s;
  }
}

// ---------------- kernel 2: segment softmax weights ----------------
static __device__ __forceinline__ int lower_bound(const int* __restrict__ batch, int key) {
  int lo = 0, hi = N_ROWS;
  while (lo < hi) { int mid = (lo + hi) >> 1; if (batch[mid] < key) lo = mid + 1; else hi = mid; }
  return lo;
}

__global__ void seg_kernel(const float* __restrict__ a, const int* __restrict__ batch,
                           float* __restrict__ w) {
  __shared__ float sm[8];
  int b = blockIdx.x;
  int start = lower_bound(batch, b);
  int end   = lower_bound(batch, b + 1);
  int tid = threadIdx.x;

  float m = -3.4e38f;
  for (int i = start + tid; i < end; i += 256) m = fmaxf(m, a[i]);
  for (int d = 1; d < 64; d <<= 1) m = fmaxf(m, __shfl_xor(m, d));
  if ((tid & 63) == 0) sm[tid >> 6] = m;
  __syncthreads();
  m = fmaxf(fmaxf(sm[0], sm[1]), fmaxf(sm[2], sm[3]));

  float s = 0.f;
  for (int i = start + tid; i < end; i += 256) s += __expf(a[i] - m);
  for (int d = 1; d < 64; d <<= 1) s += __shfl_xor(s, d);
  if ((tid & 63) == 0) sm[4 + (tid >> 6)] = s;
  __syncthreads();
  s = sm[4] + sm[5] + sm[6] + sm[7];

  float rinv = 1.0f / s;
  for (int i = start + tid; i < end; i += 256) w[i] = __expf(a[i] - m) * rinv;
}

// ---------------- kernel 3: z[b] = sum_i w_i * x_i ----------------
__global__ void z_kernel(const float* __restrict__ x, const float* __restrict__ w,
                         const int* __restrict__ batch, float* __restrict__ z) {
  int b = blockIdx.x >> 2, part = blockIdx.x & 3;
  int start = lower_bound(batch, b);
  int end   = lower_bound(batch, b + 1);
  int len = end - start;
  int ps = start + ((len * part) >> 2);
  int pe = start + ((len * (part + 1)) >> 2);
  int col = threadIdx.x << 2;

  f32x4 acc = (f32x4){0.f, 0.f, 0.f, 0.f};
  for (int i = ps; i < pe; ++i) {
    f32x4 xv = *(const f32x4*)(x + ((size_t)i << 10) + col);
    float wi = w[i];
    acc += xv * wi;
  }
  float* zp = z + ((size_t)b << 10) + col;
  atomicAdd(zp + 0, acc[0]);
  atomicAdd(zp + 1, acc[1]);
  atomicAdd(zp + 2, acc[2]);
  atomicAdd(zp + 3, acc[3]);
}

// ---------------- launch ----------------
extern "C" void kernel_launch(void* const* d_in, const int* in_sizes, int n_in,
                              void* d_out, int out_size, void* d_ws, size_t ws_size,
                              hipStream_t stream) {
  const float* x     = (const float*)d_in[0];
  const int*   batch = (const int*)d_in[1];
  const float* W1    = (const float*)d_in[2];
  const float* W2    = (const float*)d_in[3];
  const float* W3    = (const float*)d_in[4];
  float* z = (float*)d_out;

  // ws layout: [0,2MB) W1|W2 bf16 frag-major ; [2MB,3MB) a[N] f32 ; [3MB,4MB) w[N] f32
  unsigned short* wbf = (unsigned short*)d_ws;
  float* a = (float*)((char*)d_ws + (2u << 20));
  float* w = (float*)((char*)d_ws + (3u << 20));

  (void)hipMemsetAsync(d_out, 0, (size_t)N_SEG * D_DIM * sizeof(float), stream);

  cvt_w<<<512, 256, 0, stream>>>(W1, W2, wbf);

  alpha_kernel<<<N_ROWS / 64, 1024, 0, stream>>>(x, wbf, W3, a);

  seg_kernel<<<N_SEG, 256, 0, stream>>>(a, batch, w);

  z_kernel<<<N_SEG * 4, 256, 0, stream>>>(x, w, batch, z);
}